// Round 2
// baseline (292.399 us; speedup 1.0000x reference)
//
#include <hip/hip_runtime.h>

// Scatter-add via counting-sort + CSR gather.
// out = A; for each edge e: out[index[e]] += B[e]
// N_NODES=100000, N_EDGES=1250000, D=64, fp32, index int32 (harness-converted).

#define D_FEAT 64
#define SCAN_CHUNK 1024   // elements per scan block (256 threads x 4)

// ---------------- fallback (round-1) path ----------------
__global__ void scatter_add_kernel(const int* __restrict__ index,
                                   const float* __restrict__ B,
                                   float* __restrict__ out,
                                   long long total) {
    long long i = (long long)blockIdx.x * blockDim.x + threadIdx.x;
    if (i >= total) return;
    int e = (int)(i >> 6);
    int f = (int)(i & 63);
    int node = index[e];
    atomicAdd(&out[(long long)node * D_FEAT + f], B[i]);
}

// ---------------- CSR build ----------------
__global__ void hist_kernel(const int* __restrict__ index, int* __restrict__ counts,
                            int n_edges) {
    int i = blockIdx.x * blockDim.x + threadIdx.x;
    int stride = gridDim.x * blockDim.x;
    for (; i < n_edges; i += stride)
        atomicAdd(&counts[index[i]], 1);
}

// Phase A: per-block (1024-element chunk) sums
__global__ void scan_blocksums(const int* __restrict__ counts, int* __restrict__ bsums,
                               int n) {
    __shared__ int lds[256];
    int t = threadIdx.x;
    int base = blockIdx.x * SCAN_CHUNK + t * 4;
    int s = 0;
#pragma unroll
    for (int k = 0; k < 4; ++k) {
        int i = base + k;
        if (i < n) s += counts[i];
    }
    lds[t] = s;
    __syncthreads();
    for (int off = 128; off > 0; off >>= 1) {
        if (t < off) lds[t] += lds[t + off];
        __syncthreads();
    }
    if (t == 0) bsums[blockIdx.x] = lds[0];
}

// Phase B: single block exclusive-scans block sums (nb <= 256), writes grand total
__global__ void scan_bsums(int* __restrict__ bsums, int* __restrict__ total_out, int nb) {
    __shared__ int lds[256];
    int t = threadIdx.x;
    int v = (t < nb) ? bsums[t] : 0;
    lds[t] = v;
    __syncthreads();
    for (int off = 1; off < 256; off <<= 1) {
        int add = (t >= off) ? lds[t - off] : 0;
        __syncthreads();
        lds[t] += add;
        __syncthreads();
    }
    if (t < nb) bsums[t] = lds[t] - v;        // exclusive prefix
    if (t == nb - 1) *total_out = lds[t];     // offsets[n_nodes]
}

// Phase C: final exclusive scan -> offsets & heads
__global__ void scan_final(const int* __restrict__ counts, const int* __restrict__ bsums,
                           int* __restrict__ offsets, int* __restrict__ heads, int n) {
    __shared__ int lds[256];
    int t = threadIdx.x;
    int base = blockIdx.x * SCAN_CHUNK + t * 4;
    int v0 = (base + 0 < n) ? counts[base + 0] : 0;
    int v1 = (base + 1 < n) ? counts[base + 1] : 0;
    int v2 = (base + 2 < n) ? counts[base + 2] : 0;
    int v3 = (base + 3 < n) ? counts[base + 3] : 0;
    int tsum = v0 + v1 + v2 + v3;
    lds[t] = tsum;
    __syncthreads();
    for (int off = 1; off < 256; off <<= 1) {
        int add = (t >= off) ? lds[t - off] : 0;
        __syncthreads();
        lds[t] += add;
        __syncthreads();
    }
    int excl = lds[t] - tsum + bsums[blockIdx.x];
    int o0 = excl;
    int o1 = o0 + v0;
    int o2 = o1 + v1;
    int o3 = o2 + v2;
    if (base + 0 < n) { offsets[base + 0] = o0; heads[base + 0] = o0; }
    if (base + 1 < n) { offsets[base + 1] = o1; heads[base + 1] = o1; }
    if (base + 2 < n) { offsets[base + 2] = o2; heads[base + 2] = o2; }
    if (base + 3 < n) { offsets[base + 3] = o3; heads[base + 3] = o3; }
}

__global__ void place_kernel(const int* __restrict__ index, int* __restrict__ heads,
                             int* __restrict__ edge_list, int n_edges) {
    int i = blockIdx.x * blockDim.x + threadIdx.x;
    int stride = gridDim.x * blockDim.x;
    for (; i < n_edges; i += stride) {
        int node = index[i];
        int pos = atomicAdd(&heads[node], 1);
        edge_list[pos] = i;
    }
}

// ---------------- gather-accumulate ----------------
// one wave per node; lane = feature
__global__ void gather_kernel(const int* __restrict__ offsets,
                              const int* __restrict__ edge_list,
                              const float* __restrict__ A,
                              const float* __restrict__ B,
                              float* __restrict__ out, int n_nodes) {
    int wave = (int)((blockIdx.x * (long long)blockDim.x + threadIdx.x) >> 6);
    int lane = threadIdx.x & 63;
    if (wave >= n_nodes) return;
    int s = __builtin_amdgcn_readfirstlane(offsets[wave]);
    int e = __builtin_amdgcn_readfirstlane(offsets[wave + 1]);
    float acc = A[(long long)wave * D_FEAT + lane];
    for (int j = s; j < e; ++j) {
        int ed = edge_list[j];  // wave-uniform
        acc += B[(long long)ed * D_FEAT + lane];
    }
    out[(long long)wave * D_FEAT + lane] = acc;
}

extern "C" void kernel_launch(void* const* d_in, const int* in_sizes, int n_in,
                              void* d_out, int out_size, void* d_ws, size_t ws_size,
                              hipStream_t stream) {
    const int*   index = (const int*)d_in[0];   // (N_EDGES,) int32
    const float* A     = (const float*)d_in[1]; // (N_NODES, 64) f32
    const float* B     = (const float*)d_in[2]; // (N_EDGES, 64) f32
    float*       out   = (float*)d_out;         // (N_NODES, 64) f32

    const int n_edges = in_sizes[0];
    const int n_nodes = out_size / D_FEAT;
    const int nblocks_scan = (n_nodes + SCAN_CHUNK - 1) / SCAN_CHUNK;

    // ws layout (ints)
    size_t need = ((size_t)n_nodes * 2 + (size_t)(n_nodes + 1) +
                   (size_t)nblocks_scan + (size_t)n_edges) * sizeof(int);

    if (ws_size < need || nblocks_scan > 256) {
        // fallback: atomic scatter (round-1 path)
        hipMemcpyAsync(out, A, (size_t)out_size * sizeof(float),
                       hipMemcpyDeviceToDevice, stream);
        long long total = (long long)n_edges * D_FEAT;
        int block = 256;
        long long grid = (total + block - 1) / block;
        scatter_add_kernel<<<(int)grid, block, 0, stream>>>(index, B, out, total);
        return;
    }

    int* counts    = (int*)d_ws;                    // n_nodes
    int* heads     = counts + n_nodes;              // n_nodes
    int* offsets   = heads + n_nodes;               // n_nodes + 1
    int* bsums     = offsets + (n_nodes + 1);       // nblocks_scan
    int* edge_list = bsums + nblocks_scan;          // n_edges

    hipMemsetAsync(counts, 0, (size_t)n_nodes * sizeof(int), stream);

    {
        int block = 256;
        int grid = min((n_edges + block - 1) / block, 2048);
        hist_kernel<<<grid, block, 0, stream>>>(index, counts, n_edges);
    }
    scan_blocksums<<<nblocks_scan, 256, 0, stream>>>(counts, bsums, n_nodes);
    scan_bsums<<<1, 256, 0, stream>>>(bsums, &offsets[n_nodes], nblocks_scan);
    scan_final<<<nblocks_scan, 256, 0, stream>>>(counts, bsums, offsets, heads, n_nodes);
    {
        int block = 256;
        int grid = min((n_edges + block - 1) / block, 2048);
        place_kernel<<<grid, block, 0, stream>>>(index, heads, edge_list, n_edges);
    }
    {
        long long threads = (long long)n_nodes * 64;
        int block = 256;
        int grid = (int)((threads + block - 1) / block);
        gather_kernel<<<grid, block, 0, stream>>>(offsets, edge_list, A, B, out, n_nodes);
    }
}

// Round 3
// 251.601 us; speedup vs baseline: 1.1621x; 1.1621x over previous
//
#include <hip/hip_runtime.h>

// Scatter-add via counting-sort + CSR gather.
// out = A; for each edge e: out[index[e]] += B[e]
// N_NODES=100000, N_EDGES=1250000, D=64, fp32, index int32.

#define D_FEAT 64
#define SCAN_CHUNK 1024   // elements per scan block (256 threads x 4)

// ---------------- fallback (round-1) path ----------------
__global__ void scatter_add_kernel(const int* __restrict__ index,
                                   const float* __restrict__ B,
                                   float* __restrict__ out,
                                   long long total) {
    long long i = (long long)blockIdx.x * blockDim.x + threadIdx.x;
    if (i >= total) return;
    int e = (int)(i >> 6);
    int f = (int)(i & 63);
    int node = index[e];
    atomicAdd(&out[(long long)node * D_FEAT + f], B[i]);
}

// ---------------- utility ----------------
__global__ void zero_kernel(int* __restrict__ p, int n) {
    int i = blockIdx.x * blockDim.x + threadIdx.x;
    if (i < n) p[i] = 0;
}

// ---------------- CSR build ----------------
__global__ void hist_kernel(const int* __restrict__ index, int* __restrict__ counts,
                            int n_edges) {
    int i = blockIdx.x * blockDim.x + threadIdx.x;
    int stride = gridDim.x * blockDim.x;
    for (; i < n_edges; i += stride)
        atomicAdd(&counts[index[i]], 1);
}

// Phase A: per-block (1024-element chunk) sums
__global__ void scan_blocksums(const int* __restrict__ counts, int* __restrict__ bsums,
                               int n) {
    __shared__ int lds[256];
    int t = threadIdx.x;
    int base = blockIdx.x * SCAN_CHUNK + t * 4;
    int s = 0;
#pragma unroll
    for (int k = 0; k < 4; ++k) {
        int i = base + k;
        if (i < n) s += counts[i];
    }
    lds[t] = s;
    __syncthreads();
    for (int off = 128; off > 0; off >>= 1) {
        if (t < off) lds[t] += lds[t + off];
        __syncthreads();
    }
    if (t == 0) bsums[blockIdx.x] = lds[0];
}

// Phase B: single block exclusive-scans block sums (nb <= 256), writes grand total
__global__ void scan_bsums(int* __restrict__ bsums, int* __restrict__ total_out, int nb) {
    __shared__ int lds[256];
    int t = threadIdx.x;
    int v = (t < nb) ? bsums[t] : 0;
    lds[t] = v;
    __syncthreads();
    for (int off = 1; off < 256; off <<= 1) {
        int add = (t >= off) ? lds[t - off] : 0;
        __syncthreads();
        lds[t] += add;
        __syncthreads();
    }
    if (t < nb) bsums[t] = lds[t] - v;        // exclusive prefix
    if (t == nb - 1) *total_out = lds[t];     // offsets[n_nodes]
}

// Phase C: final exclusive scan -> offsets & heads
__global__ void scan_final(const int* __restrict__ counts, const int* __restrict__ bsums,
                           int* __restrict__ offsets, int* __restrict__ heads, int n) {
    __shared__ int lds[256];
    int t = threadIdx.x;
    int base = blockIdx.x * SCAN_CHUNK + t * 4;
    int v0 = (base + 0 < n) ? counts[base + 0] : 0;
    int v1 = (base + 1 < n) ? counts[base + 1] : 0;
    int v2 = (base + 2 < n) ? counts[base + 2] : 0;
    int v3 = (base + 3 < n) ? counts[base + 3] : 0;
    int tsum = v0 + v1 + v2 + v3;
    lds[t] = tsum;
    __syncthreads();
    for (int off = 1; off < 256; off <<= 1) {
        int add = (t >= off) ? lds[t - off] : 0;
        __syncthreads();
        lds[t] += add;
        __syncthreads();
    }
    int excl = lds[t] - tsum + bsums[blockIdx.x];
    int o0 = excl;
    int o1 = o0 + v0;
    int o2 = o1 + v1;
    int o3 = o2 + v2;
    if (base + 0 < n) { offsets[base + 0] = o0; heads[base + 0] = o0; }
    if (base + 1 < n) { offsets[base + 1] = o1; heads[base + 1] = o1; }
    if (base + 2 < n) { offsets[base + 2] = o2; heads[base + 2] = o2; }
    if (base + 3 < n) { offsets[base + 3] = o3; heads[base + 3] = o3; }
}

__global__ void place_kernel(const int* __restrict__ index, int* __restrict__ heads,
                             int* __restrict__ edge_list, int n_edges) {
    int i = blockIdx.x * blockDim.x + threadIdx.x;
    int stride = gridDim.x * blockDim.x;
    for (; i < n_edges; i += stride) {
        int node = index[i];
        int pos = atomicAdd(&heads[node], 1);
        edge_list[pos] = i;
    }
}

// ---------------- gather-accumulate ----------------
// one wave per node; lane = feature
__global__ void gather_kernel(const int* __restrict__ offsets,
                              const int* __restrict__ edge_list,
                              const float* __restrict__ A,
                              const float* __restrict__ B,
                              float* __restrict__ out, int n_nodes) {
    int wave = (int)((blockIdx.x * (long long)blockDim.x + threadIdx.x) >> 6);
    int lane = threadIdx.x & 63;
    if (wave >= n_nodes) return;
    int s = __builtin_amdgcn_readfirstlane(offsets[wave]);
    int e = __builtin_amdgcn_readfirstlane(offsets[wave + 1]);
    float acc = A[(long long)wave * D_FEAT + lane];
    int j = s;
    // 2-deep: issue both loads before the dependent adds
    for (; j + 1 < e; j += 2) {
        int e0 = edge_list[j];
        int e1 = edge_list[j + 1];
        float b0 = B[(long long)e0 * D_FEAT + lane];
        float b1 = B[(long long)e1 * D_FEAT + lane];
        acc += b0;
        acc += b1;
    }
    if (j < e) {
        int e0 = edge_list[j];
        acc += B[(long long)e0 * D_FEAT + lane];
    }
    out[(long long)wave * D_FEAT + lane] = acc;
}

extern "C" void kernel_launch(void* const* d_in, const int* in_sizes, int n_in,
                              void* d_out, int out_size, void* d_ws, size_t ws_size,
                              hipStream_t stream) {
    const int*   index = (const int*)d_in[0];   // (N_EDGES,) int32
    const float* A     = (const float*)d_in[1]; // (N_NODES, 64) f32
    const float* B     = (const float*)d_in[2]; // (N_EDGES, 64) f32
    float*       out   = (float*)d_out;         // (N_NODES, 64) f32

    const int n_edges = in_sizes[0];
    const int n_nodes = out_size / D_FEAT;
    const int nblocks_scan = (n_nodes + SCAN_CHUNK - 1) / SCAN_CHUNK;

    size_t need = ((size_t)n_nodes * 2 + (size_t)(n_nodes + 1) +
                   (size_t)nblocks_scan + (size_t)n_edges) * sizeof(int);

    if (ws_size < need || nblocks_scan > 256) {
        hipMemcpyAsync(out, A, (size_t)out_size * sizeof(float),
                       hipMemcpyDeviceToDevice, stream);
        long long total = (long long)n_edges * D_FEAT;
        int block = 256;
        long long grid = (total + block - 1) / block;
        scatter_add_kernel<<<(int)grid, block, 0, stream>>>(index, B, out, total);
        return;
    }

    int* counts    = (int*)d_ws;                    // n_nodes
    int* heads     = counts + n_nodes;              // n_nodes
    int* offsets   = heads + n_nodes;               // n_nodes + 1
    int* bsums     = offsets + (n_nodes + 1);       // nblocks_scan
    int* edge_list = bsums + nblocks_scan;          // n_edges

    // custom zero (hipMemsetAsync's fill kernel measured 186us for 400KB!)
    zero_kernel<<<(n_nodes + 255) / 256, 256, 0, stream>>>(counts, n_nodes);

    {
        int block = 256;
        int grid = min((n_edges + block - 1) / block, 2048);
        hist_kernel<<<grid, block, 0, stream>>>(index, counts, n_edges);
    }
    scan_blocksums<<<nblocks_scan, 256, 0, stream>>>(counts, bsums, n_nodes);
    scan_bsums<<<1, 256, 0, stream>>>(bsums, &offsets[n_nodes], nblocks_scan);
    scan_final<<<nblocks_scan, 256, 0, stream>>>(counts, bsums, offsets, heads, n_nodes);
    {
        int block = 256;
        int grid = min((n_edges + block - 1) / block, 2048);
        place_kernel<<<grid, block, 0, stream>>>(index, heads, edge_list, n_edges);
    }
    {
        long long threads = (long long)n_nodes * 64;
        int block = 256;
        int grid = (int)((threads + block - 1) / block);
        gather_kernel<<<grid, block, 0, stream>>>(offsets, edge_list, A, B, out, n_nodes);
    }
}